// Round 4
// baseline (491.433 us; speedup 1.0000x reference)
//
#include <hip/hip_runtime.h>

#define C 19
#define DCH 128
#define HWSZ 65536
#define TPB 256

// ws float offsets
#define WS_SUMS  0      // 2432 floats: sums[d*19+c]
#define WS_CNT   2432   // 19
#define WS_VAR   2451   // 19
#define WS_MEANS 2560   // 2432: means[d*19+c]
#define WS_VALID 4992   // 19
#define WS_SCAL  5011   // 3: loss_reg, loss_dist, t
#define WS_ZERO_END 2470

typedef float f32x4 __attribute__((ext_vector_type(4)));
typedef short bf16x8 __attribute__((ext_vector_type(8)));
union U8 { unsigned u[4]; bf16x8 v; };

__device__ inline unsigned pack_hi(float a, float b) {
    unsigned ua = __builtin_bit_cast(unsigned, a);
    unsigned ub = __builtin_bit_cast(unsigned, b);
    return (ua >> 16) | (ub & 0xFFFF0000u);
}
__device__ inline unsigned pack_lo(float a, float b) {
    unsigned ua = __builtin_bit_cast(unsigned, a);
    unsigned ub = __builtin_bit_cast(unsigned, b);
    float ra = a - __builtin_bit_cast(float, ua & 0xFFFF0000u);
    float rb = b - __builtin_bit_cast(float, ub & 0xFFFF0000u);
    return (__builtin_bit_cast(unsigned, ra) >> 16) |
           (__builtin_bit_cast(unsigned, rb) & 0xFFFF0000u);
}

__global__ void k0_init(float* __restrict__ ws) {
    int i = blockIdx.x * blockDim.x + threadIdx.x;
    if (i < WS_ZERO_END) ws[i] = 0.f;
}

// Counts: labels-only pass (2 MB), register compare-add + wave reduce.
__global__ __launch_bounds__(TPB) void k1c_counts(const int* __restrict__ labels,
                                                  float* __restrict__ ws) {
    const int t = threadIdx.x;
    const int lane = t & 63;
    float cr[C];
#pragma unroll
    for (int c = 0; c < C; ++c) cr[c] = 0.f;
    const int base = blockIdx.x * 8192;   // 64 blocks x 8192 ints
#pragma unroll
    for (int p = 0; p < 8; ++p) {
        int4 v = *reinterpret_cast<const int4*>(labels + base + (p * TPB + t) * 4);
#pragma unroll
        for (int c = 0; c < C; ++c) {
            cr[c] += (v.x == c ? 1.f : 0.f);
            cr[c] += (v.y == c ? 1.f : 0.f);
            cr[c] += (v.z == c ? 1.f : 0.f);
            cr[c] += (v.w == c ? 1.f : 0.f);
        }
    }
#pragma unroll
    for (int c = 0; c < C; ++c)
        for (int m = 1; m < 64; m <<= 1) cr[c] += __shfl_xor(cr[c], m);
    float v = cr[0];
#pragma unroll
    for (int c = 1; c < C; ++c) v = (lane == c) ? cr[c] : v;
    if (lane < C) atomicAdd(&ws[WS_CNT + lane], v);
}

// ---------------------------------------------------------------------------
// Pass 1: per-class sums via MFMA one-hot GEMM. sums[d][c] = A[d][p] * H[p][c].
// A = feats split hi/lo bf16 (truncate split, rel err ~2^-16); H = exact one-hot.
// 1024 blocks x 256 thr (4 blocks/CU). Block = (image, 512-pixel chunk), all 128 d.
// K-loop: 16 chunks of 32 px; fp32 tile staged to LDS double-buffered with XOR
// swizzle (slot = group ^ (d&7)) to break stride-128B bank alignment.
// Wave w owns d-rows [32w,32w+32): 2 d-tiles x 2 c-tiles of 16x16, 2 MFMAs
// (hi,lo) each => 8 mfma_f32_16x16x32_bf16 per chunk.
// A frag: m=lane&15, k=(lane>>4)*8+j (guide m120); C/D: col=lane&15,
// row=(lane>>4)*4+reg (m89-verified). B assumed mirror of A: n=lane&15.
// ---------------------------------------------------------------------------
#define K1_NB  1024
#define K1_PPB 512
#define K1_NCH 16

__global__ __launch_bounds__(TPB, 4) void k1_sums(const float* __restrict__ feats,
                                                  const int* __restrict__ labels,
                                                  float* __restrict__ ws) {
    __shared__ float tileA[2][DCH * 32];   // 2 x 16 KB
    __shared__ int llab[K1_PPB];           // 2 KB

    const int t = threadIdx.x;
    const int lane = t & 63;
    const int w = t >> 6;
    const int b = blockIdx.x >> 7;                 // 128 blocks per image
    const int pbase = (blockIdx.x & 127) * K1_PPB;

    if (t < K1_PPB / 4)
        *reinterpret_cast<int4*>(&llab[t * 4]) =
            *reinterpret_cast<const int4*>(labels + b * HWSZ + pbase + t * 4);

    const int sd = t >> 3;     // staging row base (0..31), +32 per pass
    const int sg = t & 7;      // global px-group (sequential -> coalesced row)
    const float* fbase = feats + (((size_t)b * DCH) << 16) + pbase;

    auto stage = [&](int buf, int n) {
#pragma unroll
        for (int pass = 0; pass < 4; ++pass) {
            int d = sd + pass * 32;
            float4 x = *reinterpret_cast<const float4*>(
                fbase + (((size_t)d) << 16) + n * 32 + sg * 4);
            int ps = sg ^ (d & 7);   // XOR swizzle slot
            *reinterpret_cast<float4*>(&tileA[buf][d * 32 + ps * 4]) = x;
        }
    };

    f32x4 acc[2][2] = {};            // [d-tile][c-tile]
    const int q8 = lane >> 4;        // k-offset / 8
    const int cc0 = lane & 15;       // c for c-tile 0
    const int cc1 = 16 + cc0;        // c for c-tile 1 (19..31 unused -> zero)

    stage(0, 0);
    for (int n = 0; n < K1_NCH; ++n) {
        __syncthreads();
        if (n + 1 < K1_NCH) stage((n + 1) & 1, n + 1);
        const float* tb = tileA[n & 1];

        // B one-hot fragments (k = q8*8 + j)
        const int* lp = &llab[n * 32 + q8 * 8];
        int4 la = *reinterpret_cast<const int4*>(lp);
        int4 lb = *reinterpret_cast<const int4*>(lp + 4);
        int lv[8] = {la.x, la.y, la.z, la.w, lb.x, lb.y, lb.z, lb.w};
        U8 B0, B1;
#pragma unroll
        for (int j = 0; j < 4; ++j) {
            B0.u[j] = (lv[2*j] == cc0 ? 0x3F80u : 0u) | (lv[2*j+1] == cc0 ? 0x3F800000u : 0u);
            B1.u[j] = (lv[2*j] == cc1 ? 0x3F80u : 0u) | (lv[2*j+1] == cc1 ? 0x3F800000u : 0u);
        }

#pragma unroll
        for (int dt = 0; dt < 2; ++dt) {
            int d_row = 32 * w + 16 * dt + cc0;
            const float* rp = tb + d_row * 32;
            int s = d_row & 7;
            float4 xa = *reinterpret_cast<const float4*>(rp + (((2 * q8)     ^ s) * 4));
            float4 xb = *reinterpret_cast<const float4*>(rp + (((2 * q8 + 1) ^ s) * 4));
            U8 Ah, Al;
            Ah.u[0] = pack_hi(xa.x, xa.y); Ah.u[1] = pack_hi(xa.z, xa.w);
            Ah.u[2] = pack_hi(xb.x, xb.y); Ah.u[3] = pack_hi(xb.z, xb.w);
            Al.u[0] = pack_lo(xa.x, xa.y); Al.u[1] = pack_lo(xa.z, xa.w);
            Al.u[2] = pack_lo(xb.x, xb.y); Al.u[3] = pack_lo(xb.z, xb.w);
            acc[dt][0] = __builtin_amdgcn_mfma_f32_16x16x32_bf16(Ah.v, B0.v, acc[dt][0], 0, 0, 0);
            acc[dt][0] = __builtin_amdgcn_mfma_f32_16x16x32_bf16(Al.v, B0.v, acc[dt][0], 0, 0, 0);
            acc[dt][1] = __builtin_amdgcn_mfma_f32_16x16x32_bf16(Ah.v, B1.v, acc[dt][1], 0, 0, 0);
            acc[dt][1] = __builtin_amdgcn_mfma_f32_16x16x32_bf16(Al.v, B1.v, acc[dt][1], 0, 0, 0);
        }
    }

    // flush: D row = q8*4 + r, col = c
#pragma unroll
    for (int dt = 0; dt < 2; ++dt) {
#pragma unroll
        for (int r = 0; r < 4; ++r) {
            int d = 32 * w + 16 * dt + q8 * 4 + r;
            atomicAdd(&ws[WS_SUMS + d * C + cc0], acc[dt][0][r]);
            if (cc0 < 3) atomicAdd(&ws[WS_SUMS + d * C + cc1], acc[dt][1][r]);
        }
    }
}

// Pass 2: means, valid mask, loss_reg, loss_dist, t. Single block. (unchanged)
__global__ __launch_bounds__(TPB) void k2_means(float* __restrict__ ws) {
    __shared__ float lm[DCH * C];
    __shared__ float lcnt[C];
    __shared__ float lvalid[C];
    __shared__ float lreg;
    __shared__ float ldist;
    __shared__ int   llast;
    __shared__ float ltv;
    int t = threadIdx.x;
    if (t == 0) { lreg = 0.f; ldist = 0.f; }
    if (t < C) {
        float c = ws[WS_CNT + t];
        lcnt[t] = c;
        lvalid[t] = (c > 100.f) ? 1.f : 0.f;
    }
    __syncthreads();
    for (int i = t; i < DCH * C; i += TPB) {
        int c = i % C;
        float m = ws[WS_SUMS + i] / fmaxf(lcnt[c], 1.f);
        lm[i] = m;
        ws[WS_MEANS + i] = m;
    }
    if (t == 0) {
        float tv = 0.f; int last = -1;
        for (int c2 = 0; c2 < C; ++c2) if (lvalid[c2] > 0.5f) { tv += 1.f; last = c2; }
        ltv = tv; llast = last;
    }
    __syncthreads();
    if (t < C) {
        float s = 0.f;
        for (int d = 0; d < DCH; ++d) { float m = lm[d * C + t]; s += m * m; }
        float nrm = (s > 0.f) ? sqrtf(s) : 0.f;
        if (lvalid[t] > 0.5f) atomicAdd(&lreg, nrm);
    }
    for (int pr = t; pr < C * C; pr += TPB) {
        int a = pr / C, b2 = pr % C;
        if (lvalid[a] > 0.5f && lvalid[b2] > 0.5f && b2 != llast) {
            float s = 0.f;
            for (int d = 0; d < DCH; ++d) {
                float df = lm[d * C + a] - lm[d * C + b2];
                s += df * df;
            }
            float nrm = (s > 0.f) ? sqrtf(s) : 0.f;
            float hd = fmaxf(3.0f - nrm, 0.f);   // 2*DELTA_D = 3.0
            atomicAdd(&ldist, hd * hd);
        }
    }
    __syncthreads();
    if (t < C) ws[WS_VALID + t] = lvalid[t];
    if (t == 0) {
        ws[WS_SCAL + 0] = lreg;
        ws[WS_SCAL + 1] = ldist;
        ws[WS_SCAL + 2] = ltv;
    }
}

// Pass 3: per-pixel hinged distance to class mean. (unchanged from r3)
#define K3_NB 2048
#define MPAD 20

__global__ __launch_bounds__(TPB) void k3_var(const float* __restrict__ feats,
                                              const int* __restrict__ labels,
                                              float* __restrict__ ws) {
    __shared__ float lmS[DCH * MPAD];
    __shared__ float lvalid[C];
    __shared__ float lvar[C];
    const int t = threadIdx.x;
    for (int i = t; i < DCH * C; i += TPB) {
        int d = i / C, c = i - d * C;
        lmS[d * MPAD + c] = ws[WS_MEANS + i];
    }
    if (t < C) { lvalid[t] = ws[WS_VALID + t]; lvar[t] = 0.f; }
    __syncthreads();

    const int qloc = t >> 2;
    const int k = t & 3;
    const int q = blockIdx.x * 64 + qloc;
    const int b = q >> 14;
    const int p = (q & 16383) * 4;

    const int4 lab4 = *reinterpret_cast<const int4*>(labels + b * HWSZ + p);
    const int l0 = lab4.x < 0 ? 0 : lab4.x;
    const int l1 = lab4.y < 0 ? 0 : lab4.y;
    const int l2 = lab4.z < 0 ? 0 : lab4.z;
    const int l3 = lab4.w < 0 ? 0 : lab4.w;

    const float* fb = feats + (((size_t)(b * DCH + k * 32)) << 16) + p;
    float a0 = 0.f, a1 = 0.f, a2 = 0.f, a3 = 0.f;
    for (int i = 0; i < 32; i += 8) {
        float4 xb[8];
#pragma unroll
        for (int u = 0; u < 8; ++u)
            xb[u] = *reinterpret_cast<const float4*>(fb + ((size_t)(i + u) << 16));
#pragma unroll
        for (int u = 0; u < 8; ++u) {
            const float* mr = &lmS[(k * 32 + i + u) * MPAD];
            float d0 = xb[u].x - mr[l0]; a0 = fmaf(d0, d0, a0);
            float d1 = xb[u].y - mr[l1]; a1 = fmaf(d1, d1, a1);
            float d2 = xb[u].z - mr[l2]; a2 = fmaf(d2, d2, a2);
            float d3 = xb[u].w - mr[l3]; a3 = fmaf(d3, d3, a3);
        }
    }
    a0 += __shfl_xor(a0, 1); a0 += __shfl_xor(a0, 2);
    a1 += __shfl_xor(a1, 1); a1 += __shfl_xor(a1, 2);
    a2 += __shfl_xor(a2, 1); a2 += __shfl_xor(a2, 2);
    a3 += __shfl_xor(a3, 1); a3 += __shfl_xor(a3, 2);

    if (k == 0) {
        auto hinge2 = [&](float a, int rawlab, int l) -> float {
            float nrm = (a > 0.f) ? sqrtf(a) : 0.f;
            float h = fmaxf(nrm - 0.5f, 0.f);      // DELTA_V = 0.5
            float v = h * h;
            return (rawlab >= 0 && lvalid[l] > 0.5f) ? v : 0.f;
        };
        atomicAdd(&lvar[l0], hinge2(a0, lab4.x, l0));
        atomicAdd(&lvar[l1], hinge2(a1, lab4.y, l1));
        atomicAdd(&lvar[l2], hinge2(a2, lab4.z, l2));
        atomicAdd(&lvar[l3], hinge2(a3, lab4.w, l3));
    }
    __syncthreads();
    if (t < C) atomicAdd(&ws[WS_VAR + t], lvar[t]);
}

// Pass 4: final scalar. (unchanged)
__global__ void k4_final(const float* __restrict__ ws, float* __restrict__ out) {
    if (threadIdx.x == 0) {
        float loss_var = 0.f;
        for (int c = 0; c < C; ++c) {
            float cnt = ws[WS_CNT + c];
            float v = ws[WS_VAR + c] / fmaxf(cnt, 1.f);
            if (ws[WS_VALID + c] > 0.5f) loss_var += v;
        }
        float reg  = ws[WS_SCAL + 0];
        float dist = ws[WS_SCAL + 1];
        float tv   = ws[WS_SCAL + 2];
        float loss = loss_var / tv + dist / (tv * (tv - 1.0f)) + 0.001f * reg / tv;
        out[0] = loss;
    }
}

extern "C" void kernel_launch(void* const* d_in, const int* in_sizes, int n_in,
                              void* d_out, int out_size, void* d_ws, size_t ws_size,
                              hipStream_t stream) {
    const float* feats  = (const float*)d_in[0];
    const int*   labels = (const int*)d_in[1];
    float* ws  = (float*)d_ws;
    float* out = (float*)d_out;

    hipLaunchKernelGGL(k0_init,  dim3((WS_ZERO_END + 255) / 256), dim3(256), 0, stream, ws);
    hipLaunchKernelGGL(k1c_counts, dim3(64), dim3(TPB), 0, stream, labels, ws);
    hipLaunchKernelGGL(k1_sums,  dim3(K1_NB), dim3(TPB), 0, stream, feats, labels, ws);
    hipLaunchKernelGGL(k2_means, dim3(1),   dim3(TPB), 0, stream, ws);
    hipLaunchKernelGGL(k3_var,   dim3(K3_NB), dim3(TPB), 0, stream, feats, labels, ws);
    hipLaunchKernelGGL(k4_final, dim3(1),   dim3(64),  0, stream, ws, out);
}